// Round 2
// baseline (297.179 us; speedup 1.0000x reference)
//
#include <hip/hip_runtime.h>
#include <hip/hip_bf16.h>

#define N_NODES 100000
#define N_EDGES 800000
#define D 64
#define SCAN_B 256
#define NB1 ((N_NODES + SCAN_B - 1) / SCAN_B)   // 391 blocks
#define FILL_BLOCKS (N_EDGES / 256)             // 3125, exact
#define INIT_BLOCKS (N_NODES * D / 256)         // 25000, exact
#define CT 64                                   // conv tile: nodes per block
#define XS 68                                   // fp32 LDS row stride (bank-safe)
#define OS 72                                   // u16 LDS out row stride (144 B = 16B-aligned rows)

using bf16x8 = __attribute__((ext_vector_type(8))) short;
using f32x4  = __attribute__((ext_vector_type(4))) float;

// bf16 helpers: storage-only bf16 (embeds, x); all math fp32/MFMA-fp32-accum.
__device__ __forceinline__ unsigned short f2bf(float f) {
    union { float f; unsigned u; } v; v.f = f;
    unsigned r = v.u + 0x7fffu + ((v.u >> 16) & 1u);   // round-to-nearest-even
    return (unsigned short)(r >> 16);
}
__device__ __forceinline__ float bf2f(unsigned short u) {
    return __uint_as_float(((unsigned)u) << 16);
}
__device__ __forceinline__ void acc_bf8(float acc[8], uint4 u) {
    acc[0] += __uint_as_float(u.x << 16);
    acc[1] += __uint_as_float(u.x & 0xffff0000u);
    acc[2] += __uint_as_float(u.y << 16);
    acc[3] += __uint_as_float(u.y & 0xffff0000u);
    acc[4] += __uint_as_float(u.z << 16);
    acc[5] += __uint_as_float(u.z & 0xffff0000u);
    acc[6] += __uint_as_float(u.w << 16);
    acc[7] += __uint_as_float(u.w & 0xffff0000u);
}
__device__ __forceinline__ unsigned pack2bf(float a, float b) {
    return (unsigned)f2bf(a) | ((unsigned)f2bf(b) << 16);
}

// ---------------------------------------------------------------------------
// hist: deg[dst]++ only (rank array removed; fill uses cursor atomics).
__global__ __launch_bounds__(256) void hist_kernel(
        const int2* __restrict__ edges,
        int* __restrict__ deg) {
    int t = blockIdx.x * 256 + threadIdx.x;
    int2 e = edges[t];                      // grid exact: 3125*256 == N_EDGES
    atomicAdd(&deg[e.y], 1);
}

// ---------------------------------------------------------------------------
// scan1: block-local exclusive scan over deg -> row_ptr, emit block totals.
__global__ void scan1_kernel(const int* __restrict__ deg,
                             int* __restrict__ row_ptr,
                             int* __restrict__ bsum) {
    __shared__ int tmp[SCAN_B];
    int t = threadIdx.x;
    int i = blockIdx.x * SCAN_B + t;
    int v = (i < N_NODES) ? deg[i] : 0;
    tmp[t] = v;
    __syncthreads();
#pragma unroll
    for (int off = 1; off < SCAN_B; off <<= 1) {
        int a = (t >= off) ? tmp[t - off] : 0;
        __syncthreads();
        tmp[t] += a;
        __syncthreads();
    }
    if (i < N_NODES) row_ptr[i] = tmp[t] - v;   // exclusive
    if (t == SCAN_B - 1) bsum[blockIdx.x] = tmp[t];
}

// scan2+scan3 merged: each block reduce-sums bsum[0..blockIdx-1] (391 ints),
// adds it to its 256 row_ptr entries, and emits a cursor copy for the fill.
__global__ void scan23_kernel(int* __restrict__ row_ptr,
                              const int* __restrict__ bsum,
                              int* __restrict__ cursor) {
    __shared__ int red[SCAN_B];
    int t = threadIdx.x;
    int partial = 0;
    if (t < blockIdx.x && t < NB1) partial += bsum[t];
    int t2 = t + 256;
    if (t2 < blockIdx.x && t2 < NB1) partial += bsum[t2];
    red[t] = partial;
    __syncthreads();
#pragma unroll
    for (int off = 128; off > 0; off >>= 1) {
        if (t < off) red[t] += red[t + off];
        __syncthreads();
    }
    int boff = red[0];
    int i = blockIdx.x * SCAN_B + t;
    if (i < N_NODES) {
        int v = row_ptr[i] + boff;
        row_ptr[i] = v;
        cursor[i] = v;
    }
    if (i == 0) row_ptr[N_NODES] = N_EDGES;
}

// ---------------------------------------------------------------------------
// Fused dispatch: blocks [0, FILL_BLOCKS) scatter CSR cols via cursor atomics
// (order within a row is irrelevant: downstream is a sum); blocks
// [FILL_BLOCKS, +INIT_BLOCKS) compute initial embeddings (bf16); one extra
// block splits conv1_W into bf16 hi/lo (W ~= Whi + Wlo to fp32 precision)
// for the MFMA conv.
__global__ __launch_bounds__(256) void fill_init_kernel(
        const int2* __restrict__ edges,
        int* __restrict__ cursor,
        int* __restrict__ col,
        const int* __restrict__ nodes,
        const float* __restrict__ features,
        const float* __restrict__ node_emb,
        const float* __restrict__ feat_W,
        const float* __restrict__ feat_b,
        unsigned short* __restrict__ embeds,
        const float* __restrict__ conv1_W,
        unsigned short* __restrict__ Whi,
        unsigned short* __restrict__ Wlo) {
    if (blockIdx.x < FILL_BLOCKS) {
        int t = blockIdx.x * 256 + threadIdx.x;
        int2 e = edges[t];
        col[atomicAdd(&cursor[e.y], 1)] = e.x;
    } else if (blockIdx.x < FILL_BLOCKS + INIT_BLOCKS) {
        int tid = (blockIdx.x - FILL_BLOCKS) * 256 + threadIdx.x;
        int node = tid >> 6;
        int d = tid & 63;
        float acc = feat_b[d];
        const float* f = features + (size_t)node * 10;
        const float* w = feat_W + (size_t)d * 10;
#pragma unroll
        for (int j = 0; j < 10; ++j) acc += f[j] * w[j];
        embeds[tid] = f2bf(node_emb[(size_t)nodes[node] * D + d] + acc);
    } else {
        // split W: 4096 elems, 16 per thread, coalesced
        int t = threadIdx.x;
#pragma unroll
        for (int j = 0; j < 16; ++j) {
            int i = t + 256 * j;
            float w = conv1_W[i];
            unsigned short hi = f2bf(w);
            Whi[i] = hi;
            Wlo[i] = f2bf(w - bf2f(hi));
        }
    }
}

// ---------------------------------------------------------------------------
// x[node] = emb_in[node] + sum_{src} emb_in[src]   (emb bf16, acc fp32,
// OUTPUT bf16). One WAVE per node (uniform trips). 8 groups x 8 lanes:
// group g loads the row of src (r*8+g) as uint4 (8 bf16 = 16 B/lane,
// 128 B/row coalesced). Best-measured gather structure (prev session r9/r12);
// launch_bounds(256,8) caps 64 VGPR -> 8 waves/SIMD: the gather is
// latency/concurrency-bound, not byte-bound. DO NOT fuse with conv: R1
// measured -21 us from losing 100K-wave parallelism.
__global__ __launch_bounds__(256, 8) void gather_x_kernel(
        const unsigned short* __restrict__ emb_in,
        const int* __restrict__ rowp,
        const int* __restrict__ col,
        unsigned short* __restrict__ x_out) {
    int lane = threadIdx.x & 63;
    int wv   = threadIdx.x >> 6;
    int node = blockIdx.x * 4 + wv;          // grid = 25000, exact
    int g = lane >> 3;                        // row-group 0..7
    int c = lane & 7;                         // uint4 chunk 0..7

    int start = rowp[node];
    int end   = rowp[node + 1];

    float acc[8];
#pragma unroll
    for (int j = 0; j < 8; ++j) acc[j] = 0.f;
    if (g == 0) {                             // self term, counted once
        uint4 u = ((const uint4*)(emb_in + (size_t)node * D))[c];
        acc_bf8(acc, u);
    }

    for (int base = start; base < end; base += 32) {
        int nb = end - base; if (nb > 32) nb = 32;
        int idx = (lane < nb) ? col[base + lane] : 0;   // lanes 0..31, coalesced
#pragma unroll
        for (int r = 0; r < 4; ++r) {
            int s = r * 8 + g;                          // 0..31
            int src = __shfl(idx, s, 64);               // all lanes active
            if (s < nb) {                               // per-lane predication
                uint4 u = ((const uint4*)(emb_in + (size_t)src * D))[c];
                acc_bf8(acc, u);
            }
        }
    }

    // combine the 8 group partials (xor 8, 16, 32)
#pragma unroll
    for (int m = 8; m <= 32; m <<= 1) {
#pragma unroll
        for (int j = 0; j < 8; ++j) acc[j] += __shfl_xor(acc[j], m, 64);
    }

    if (g == 0) {                             // 8 lanes x 16 B = 128 B bf16 row
        uint4 p;
        p.x = pack2bf(acc[0], acc[1]);
        p.y = pack2bf(acc[2], acc[3]);
        p.z = pack2bf(acc[4], acc[5]);
        p.w = pack2bf(acc[6], acc[7]);
        ((uint4*)(x_out + (size_t)node * D))[c] = p;
    }
}

// ---------------------------------------------------------------------------
// MFMA conv: y = relu(x @ W^T + b) via mfma_f32_16x16x32_bf16, W in bf16
// hi/lo split (2 MFMAs per k-step -> fp32-accurate W). No X/W LDS staging:
// A-frags load straight from global x (lane: row=lane&15, k=(lane>>4)*8+j),
// B-frags from Whi/Wlo rows (lane: col=lane&15, k=(lane>>4)*8+j) — W is
// 8 KB x2, L1/L2-hot across all blocks. C/D layout (m89-verified):
// col=lane&15, row=(lane>>4)*4+reg. 4 waves x 16 nodes = 64 nodes/block.
// !SCORE: bf16 pack via LDS transpose -> coalesced uint4 stores.
// SCORE: fp32 y via LDS, wave0 per-node cosine vs pattern -> score_out.
template <bool SCORE>
__global__ __launch_bounds__(256) void conv_mfma_kernel(
        const unsigned short* __restrict__ x,
        const unsigned short* __restrict__ Whi,
        const unsigned short* __restrict__ Wlo,
        const float* __restrict__ b,
        const float* __restrict__ pattern_emb,
        const int* __restrict__ pattern_id,
        unsigned short* __restrict__ emb_out,
        float* __restrict__ score_out) {
    __shared__ union {
        unsigned short Os[CT][OS];   // 9216 B  (!SCORE epilogue)
        float Ys[CT][XS];            // 17408 B (SCORE epilogue)
    } u;
    __shared__ float ps[D];

    int t = threadIdx.x;
    int lane = t & 63;
    int wv = t >> 6;                          // wave 0..3
    int base = blockIdx.x * CT;
    int nodebase = base + wv * 16;
    int row16 = lane & 15;                    // A-row / B-col within tile
    int kq = lane >> 4;                       // k-quarter 0..3

    if (SCORE && t < D) ps[t] = pattern_emb[(size_t)pattern_id[0] * D + t];

    // A fragments (k-steps 0,1). Rows >= N_NODES (last block tail) read
    // in-workspace garbage; their outputs are predicated off below.
    const bf16x8* xp = (const bf16x8*)(x + (size_t)(nodebase + row16) * D + kq * 8);
    bf16x8 a0 = xp[0];                        // k = kq*8 .. +7
    bf16x8 a1 = xp[4];                        // k = 32 + kq*8 .. +7

    f32x4 acc[4] = {};
    float bj[4];
#pragma unroll
    for (int tc = 0; tc < 4; ++tc) {
        int o = tc * 16 + row16;              // output dim for this lane/tile
        bj[tc] = b[o];
        const bf16x8* wh = (const bf16x8*)(Whi + (size_t)o * D + kq * 8);
        const bf16x8* wl = (const bf16x8*)(Wlo + (size_t)o * D + kq * 8);
        acc[tc] = __builtin_amdgcn_mfma_f32_16x16x32_bf16(a0, wh[0], acc[tc], 0, 0, 0);
        acc[tc] = __builtin_amdgcn_mfma_f32_16x16x32_bf16(a1, wh[4], acc[tc], 0, 0, 0);
        acc[tc] = __builtin_amdgcn_mfma_f32_16x16x32_bf16(a0, wl[0], acc[tc], 0, 0, 0);
        acc[tc] = __builtin_amdgcn_mfma_f32_16x16x32_bf16(a1, wl[4], acc[tc], 0, 0, 0);
    }

    if (!SCORE) {
#pragma unroll
        for (int tc = 0; tc < 4; ++tc)
#pragma unroll
            for (int r = 0; r < 4; ++r)
                u.Os[wv * 16 + kq * 4 + r][tc * 16 + row16] =
                    f2bf(fmaxf(acc[tc][r] + bj[tc], 0.f));
        __syncthreads();
#pragma unroll
        for (int q = 0; q < 2; ++q) {
            int idx = t + q * 256;            // 0..511: 64 rows x 8 uint4 segs
            int r = idx >> 3, seg = idx & 7;
            int node = base + r;
            if (node < N_NODES)
                ((uint4*)(emb_out + (size_t)node * D))[seg] = *((const uint4*)&u.Os[r][8 * seg]);
        }
    } else {
#pragma unroll
        for (int tc = 0; tc < 4; ++tc)
#pragma unroll
            for (int r = 0; r < 4; ++r)
                u.Ys[wv * 16 + kq * 4 + r][tc * 16 + row16] = fmaxf(acc[tc][r] + bj[tc], 0.f);
        __syncthreads();
        if (t < CT) {                         // wave 0: one lane per node
            float dot = 0.f, n2 = 0.f, pn = 0.f;
#pragma unroll 8
            for (int k = 0; k < D; ++k) {
                float yk = u.Ys[t][k];
                float pk = ps[k];
                dot += yk * pk; n2 += yk * yk; pn += pk * pk;
            }
            int node = base + t;
            if (node < N_NODES)
                score_out[node] = dot / (fmaxf(sqrtf(n2), 1e-8f) * fmaxf(sqrtf(pn), 1e-8f));
        }
    }
}

// ---------------------------------------------------------------------------
// Fallback path (atomic scatter, full fp32) if ws too small for CSR arrays.
__global__ void init_embeds_kernel(const int* __restrict__ nodes,
                                   const float* __restrict__ features,
                                   const float* __restrict__ node_emb,
                                   const float* __restrict__ feat_W,
                                   const float* __restrict__ feat_b,
                                   float* __restrict__ embeds) {
    int tid = blockIdx.x * blockDim.x + threadIdx.x;
    if (tid >= N_NODES * D) return;
    int node = tid >> 6;
    int d = tid & 63;
    float acc = feat_b[d];
    const float* f = features + (size_t)node * 10;
    const float* w = feat_W + (size_t)d * 10;
#pragma unroll
    for (int j = 0; j < 10; ++j) acc += f[j] * w[j];
    embeds[tid] = node_emb[(size_t)nodes[node] * D + d] + acc;
}

__global__ void scatter_add_kernel(const int* __restrict__ edges,
                                   const float* __restrict__ embeds,
                                   float* __restrict__ agg) {
    int tid = blockIdx.x * blockDim.x + threadIdx.x;
    int edge = tid >> 6;
    int lane = tid & 63;
    if (edge >= N_EDGES) return;
    int src = edges[2 * edge + 0];
    int dst = edges[2 * edge + 1];
    atomicAdd(&agg[(size_t)dst * D + lane], embeds[(size_t)src * D + lane]);
}

__global__ void conv_inplace_kernel(const float* __restrict__ agg,
                                    const float* __restrict__ W,
                                    const float* __restrict__ b,
                                    float* __restrict__ embeds) {
    __shared__ float Ws[D * 65];
    __shared__ float xs[4][D];
    for (int i = threadIdx.x; i < D * D; i += blockDim.x) {
        int d = i >> 6, k = i & 63;
        Ws[d * 65 + k] = W[i];
    }
    __syncthreads();
    int lane_d = threadIdx.x & 63;
    int local_n = threadIdx.x >> 6;
    float bias = b[lane_d];
    const int n_chunks = (N_NODES + 3) / 4;
    for (int chunk = blockIdx.x; chunk < n_chunks; chunk += gridDim.x) {
        int node = chunk * 4 + local_n;
        if (node < N_NODES) {
            size_t base = (size_t)node * D + lane_d;
            xs[local_n][lane_d] = embeds[base] + agg[base];
        }
        __syncthreads();
        if (node < N_NODES) {
            float acc = bias;
#pragma unroll
            for (int k = 0; k < D; ++k) acc += xs[local_n][k] * Ws[lane_d * 65 + k];
            embeds[(size_t)node * D + lane_d] = fmaxf(acc, 0.0f);
        }
        __syncthreads();
    }
}

__global__ void final_score_kernel(const float* __restrict__ embeds,
                                   const float* __restrict__ pattern_emb,
                                   const int* __restrict__ pattern_id,
                                   float* __restrict__ out) {
    int lane = threadIdx.x & 63;
    int wave = threadIdx.x >> 6;
    int node = blockIdx.x * 4 + wave;
    int pid = pattern_id[0];
    float p = pattern_emb[(size_t)pid * D + lane];
    float pn = p * p;
#pragma unroll
    for (int m = 32; m > 0; m >>= 1) pn += __shfl_xor(pn, m, 64);
    if (node < N_NODES) {
        float e = embeds[(size_t)node * D + lane];
        float dot = e * p;
        float n2 = e * e;
#pragma unroll
        for (int m = 32; m > 0; m >>= 1) {
            dot += __shfl_xor(dot, m, 64);
            n2  += __shfl_xor(n2, m, 64);
        }
        if (lane == 0) {
            float denom = fmaxf(sqrtf(n2), 1e-8f) * fmaxf(sqrtf(pn), 1e-8f);
            out[node] = dot / denom;
        }
    }
}

// ---------------------------------------------------------------------------
extern "C" void kernel_launch(void* const* d_in, const int* in_sizes, int n_in,
                              void* d_out, int out_size, void* d_ws, size_t ws_size,
                              hipStream_t stream) {
    const int*   nodes       = (const int*)d_in[0];
    const int*   edges       = (const int*)d_in[1];
    const float* features    = (const float*)d_in[2];
    const float* node_emb    = (const float*)d_in[3];
    const float* feat_W      = (const float*)d_in[4];
    const float* feat_b      = (const float*)d_in[5];
    const float* conv1_W     = (const float*)d_in[6];
    const float* conv1_b     = (const float*)d_in[7];
    const float* pattern_emb = (const float*)d_in[8];
    const int*   pattern_id  = (const int*)d_in[9];
    float* out = (float*)d_out;

    const size_t emb_f32_bytes = (size_t)N_NODES * D * sizeof(float);   // 25.6 MB
    const size_t emb_bf_bytes  = (size_t)N_NODES * D * 2;               // 12.8 MB
    auto align256 = [](size_t x) { return (x + 255) & ~(size_t)255; };

    size_t o_embA = 0;
    size_t o_embB = o_embA + align256(emb_bf_bytes);
    size_t o_xbuf = o_embB + align256(emb_bf_bytes);
    size_t o_col  = o_xbuf + align256(emb_bf_bytes);
    size_t o_row  = o_col  + align256((size_t)N_EDGES * 4);
    size_t o_cur  = o_row  + align256((size_t)(N_NODES + 1) * 4);
    size_t o_deg  = o_cur  + align256((size_t)N_NODES * 4);
    size_t o_bsum = o_deg  + align256((size_t)N_NODES * 4);
    size_t o_whi  = o_bsum + align256((size_t)NB1 * 4);
    size_t o_wlo  = o_whi  + align256((size_t)D * D * 2);
    size_t need   = o_wlo  + align256((size_t)D * D * 2);

    char* ws = (char*)d_ws;

    if (ws_size >= need) {
        unsigned short* embA = (unsigned short*)(ws + o_embA);
        unsigned short* embB = (unsigned short*)(ws + o_embB);
        unsigned short* xbuf = (unsigned short*)(ws + o_xbuf);
        int*   col  = (int*)(ws + o_col);
        int*   rowp = (int*)(ws + o_row);
        int*   cur  = (int*)(ws + o_cur);
        int*   deg  = (int*)(ws + o_deg);
        int*   bsum = (int*)(ws + o_bsum);
        unsigned short* Whi = (unsigned short*)(ws + o_whi);
        unsigned short* Wlo = (unsigned short*)(ws + o_wlo);

        hipMemsetAsync(deg, 0, (size_t)N_NODES * 4, stream);
        hist_kernel<<<FILL_BLOCKS, 256, 0, stream>>>((const int2*)edges, deg);
        scan1_kernel<<<NB1, SCAN_B, 0, stream>>>(deg, rowp, bsum);
        scan23_kernel<<<NB1, SCAN_B, 0, stream>>>(rowp, bsum, cur);
        fill_init_kernel<<<FILL_BLOCKS + INIT_BLOCKS + 1, 256, 0, stream>>>(
            (const int2*)edges, cur, col,
            nodes, features, node_emb, feat_W, feat_b, embA,
            conv1_W, Whi, Wlo);

        const int conv_grid = (N_NODES + CT - 1) / CT;   // 1563

        // iter 1: gather(bf16->bf16) + MFMA conv -> embB (bf16)
        gather_x_kernel<<<N_NODES / 4, 256, 0, stream>>>(embA, rowp, col, xbuf);
        conv_mfma_kernel<false><<<conv_grid, 256, 0, stream>>>(
            xbuf, Whi, Wlo, conv1_b, pattern_emb, pattern_id, embB, nullptr);
        // iter 2: gather + MFMA conv fused with cosine score -> out
        gather_x_kernel<<<N_NODES / 4, 256, 0, stream>>>(embB, rowp, col, xbuf);
        conv_mfma_kernel<true><<<conv_grid, 256, 0, stream>>>(
            xbuf, Whi, Wlo, conv1_b, pattern_emb, pattern_id, nullptr, out);
    } else {
        float* embeds = (float*)ws;
        float* agg = (float*)(ws + align256(emb_f32_bytes));
        init_embeds_kernel<<<(N_NODES * D + 255) / 256, 256, 0, stream>>>(
            nodes, features, node_emb, feat_W, feat_b, embeds);
        for (int it = 0; it < 2; ++it) {
            hipMemsetAsync(agg, 0, emb_f32_bytes, stream);
            long long total = (long long)N_EDGES * 64;
            scatter_add_kernel<<<(int)((total + 255) / 256), 256, 0, stream>>>(edges, embeds, agg);
            conv_inplace_kernel<<<2048, 256, 0, stream>>>(agg, conv1_W, conv1_b, embeds);
        }
        final_score_kernel<<<(N_NODES + 3) / 4, 256, 0, stream>>>(
            embeds, pattern_emb, pattern_id, out);
    }
}

// Round 3
// 256.135 us; speedup vs baseline: 1.1602x; 1.1602x over previous
//
#include <hip/hip_runtime.h>
#include <hip/hip_bf16.h>

#define N_NODES 100000
#define N_EDGES 800000
#define D 64
#define SCAN_B 256
#define NB1 ((N_NODES + SCAN_B - 1) / SCAN_B)   // 391 blocks
#define FILL_BLOCKS (N_EDGES / 256)             // 3125, exact
#define INIT_BLOCKS (N_NODES * D / 256)         // 25000, exact
#define CT 64                                   // conv tile: nodes per block
#define XS 68                                   // fp32 LDS row stride (bank-safe)
#define OS 72                                   // u16 LDS out row stride (144 B = 16B-aligned rows)

using bf16x8 = __attribute__((ext_vector_type(8))) short;
using f32x4  = __attribute__((ext_vector_type(4))) float;

// bf16 helpers: storage-only bf16 (embeds, x); all math fp32/MFMA-fp32-accum.
__device__ __forceinline__ unsigned short f2bf(float f) {
    union { float f; unsigned u; } v; v.f = f;
    unsigned r = v.u + 0x7fffu + ((v.u >> 16) & 1u);   // round-to-nearest-even
    return (unsigned short)(r >> 16);
}
__device__ __forceinline__ float bf2f(unsigned short u) {
    return __uint_as_float(((unsigned)u) << 16);
}
__device__ __forceinline__ void acc_bf8(float acc[8], uint4 u) {
    acc[0] += __uint_as_float(u.x << 16);
    acc[1] += __uint_as_float(u.x & 0xffff0000u);
    acc[2] += __uint_as_float(u.y << 16);
    acc[3] += __uint_as_float(u.y & 0xffff0000u);
    acc[4] += __uint_as_float(u.z << 16);
    acc[5] += __uint_as_float(u.z & 0xffff0000u);
    acc[6] += __uint_as_float(u.w << 16);
    acc[7] += __uint_as_float(u.w & 0xffff0000u);
}
__device__ __forceinline__ unsigned pack2bf(float a, float b) {
    return (unsigned)f2bf(a) | ((unsigned)f2bf(b) << 16);
}

// ---------------------------------------------------------------------------
// hist + rank: deg[dst]++, rank[e] = arrival order of edge e at its dst.
// NOTE (R2 post-mortem): do NOT replace this with cursor atomics inside the
// fill — the dependent atomic-return -> scattered-store chain cost +40 us
// and +50 MB of writebacks. Rank-based two-pass is the measured winner.
__global__ __launch_bounds__(256) void hist_rank_kernel(
        const int2* __restrict__ edges,
        int* __restrict__ deg,
        int* __restrict__ rank) {
    int t = blockIdx.x * 256 + threadIdx.x;
    int2 e = edges[t];                      // grid exact: 3125*256 == N_EDGES
    rank[t] = atomicAdd(&deg[e.y], 1);
}

// ---------------------------------------------------------------------------
// scan1: block-local exclusive scan over deg -> row_ptr, emit block totals.
__global__ void scan1_kernel(const int* __restrict__ deg,
                             int* __restrict__ row_ptr,
                             int* __restrict__ bsum) {
    __shared__ int tmp[SCAN_B];
    int t = threadIdx.x;
    int i = blockIdx.x * SCAN_B + t;
    int v = (i < N_NODES) ? deg[i] : 0;
    tmp[t] = v;
    __syncthreads();
#pragma unroll
    for (int off = 1; off < SCAN_B; off <<= 1) {
        int a = (t >= off) ? tmp[t - off] : 0;
        __syncthreads();
        tmp[t] += a;
        __syncthreads();
    }
    if (i < N_NODES) row_ptr[i] = tmp[t] - v;   // exclusive
    if (t == SCAN_B - 1) bsum[blockIdx.x] = tmp[t];
}

// scan2+scan3 merged: each block reduce-sums bsum[0..blockIdx-1] (391 ints)
// and adds it to its 256 row_ptr entries.
__global__ void scan23_kernel(int* __restrict__ row_ptr,
                              const int* __restrict__ bsum) {
    __shared__ int red[SCAN_B];
    int t = threadIdx.x;
    int partial = 0;
    if (t < blockIdx.x && t < NB1) partial += bsum[t];
    int t2 = t + 256;
    if (t2 < blockIdx.x && t2 < NB1) partial += bsum[t2];
    red[t] = partial;
    __syncthreads();
#pragma unroll
    for (int off = 128; off > 0; off >>= 1) {
        if (t < off) red[t] += red[t + off];
        __syncthreads();
    }
    int boff = red[0];
    int i = blockIdx.x * SCAN_B + t;
    if (i < N_NODES) row_ptr[i] += boff;
    if (i == 0) row_ptr[N_NODES] = N_EDGES;
}

// ---------------------------------------------------------------------------
// Fused dispatch: blocks [0, FILL_BLOCKS) scatter CSR cols (atomic-free via
// rank); blocks [FILL_BLOCKS, +INIT_BLOCKS) compute initial embeddings
// (bf16); one extra block splits conv1_W into bf16 hi/lo (W ~= Whi + Wlo to
// fp32 precision) for the MFMA conv.
__global__ __launch_bounds__(256) void fill_init_kernel(
        const int2* __restrict__ edges,
        const int* __restrict__ rank,
        const int* __restrict__ rowp,
        int* __restrict__ col,
        const int* __restrict__ nodes,
        const float* __restrict__ features,
        const float* __restrict__ node_emb,
        const float* __restrict__ feat_W,
        const float* __restrict__ feat_b,
        unsigned short* __restrict__ embeds,
        const float* __restrict__ conv1_W,
        unsigned short* __restrict__ Whi,
        unsigned short* __restrict__ Wlo) {
    if (blockIdx.x < FILL_BLOCKS) {
        int t = blockIdx.x * 256 + threadIdx.x;
        int2 e = edges[t];
        col[rowp[e.y] + rank[t]] = e.x;
    } else if (blockIdx.x < FILL_BLOCKS + INIT_BLOCKS) {
        int tid = (blockIdx.x - FILL_BLOCKS) * 256 + threadIdx.x;
        int node = tid >> 6;
        int d = tid & 63;
        float acc = feat_b[d];
        const float* f = features + (size_t)node * 10;
        const float* w = feat_W + (size_t)d * 10;
#pragma unroll
        for (int j = 0; j < 10; ++j) acc += f[j] * w[j];
        embeds[tid] = f2bf(node_emb[(size_t)nodes[node] * D + d] + acc);
    } else {
        // split W: 4096 elems, 16 per thread, coalesced
        int t = threadIdx.x;
#pragma unroll
        for (int j = 0; j < 16; ++j) {
            int i = t + 256 * j;
            float w = conv1_W[i];
            unsigned short hi = f2bf(w);
            Whi[i] = hi;
            Wlo[i] = f2bf(w - bf2f(hi));
        }
    }
}

// ---------------------------------------------------------------------------
// x[node] = emb_in[node] + sum_{src} emb_in[src]   (emb bf16, acc fp32,
// OUTPUT bf16). One WAVE per node (uniform trips). 8 groups x 8 lanes:
// group g loads the row of src (r*8+g) as uint4 (8 bf16 = 16 B/lane,
// 128 B/row coalesced). Best-measured gather structure; launch_bounds(256,8)
// caps 64 VGPR -> 8 waves/SIMD: latency/concurrency-bound, not byte-bound.
// DO NOT fuse with conv: R1 measured -21 us from losing 100K-wave parallelism.
__global__ __launch_bounds__(256, 8) void gather_x_kernel(
        const unsigned short* __restrict__ emb_in,
        const int* __restrict__ rowp,
        const int* __restrict__ col,
        unsigned short* __restrict__ x_out) {
    int lane = threadIdx.x & 63;
    int wv   = threadIdx.x >> 6;
    int node = blockIdx.x * 4 + wv;          // grid = 25000, exact
    int g = lane >> 3;                        // row-group 0..7
    int c = lane & 7;                         // uint4 chunk 0..7

    int start = rowp[node];
    int end   = rowp[node + 1];

    float acc[8];
#pragma unroll
    for (int j = 0; j < 8; ++j) acc[j] = 0.f;
    if (g == 0) {                             // self term, counted once
        uint4 u = ((const uint4*)(emb_in + (size_t)node * D))[c];
        acc_bf8(acc, u);
    }

    for (int base = start; base < end; base += 32) {
        int nb = end - base; if (nb > 32) nb = 32;
        int idx = (lane < nb) ? col[base + lane] : 0;   // lanes 0..31, coalesced
#pragma unroll
        for (int r = 0; r < 4; ++r) {
            int s = r * 8 + g;                          // 0..31
            int src = __shfl(idx, s, 64);               // all lanes active
            if (s < nb) {                               // per-lane predication
                uint4 u = ((const uint4*)(emb_in + (size_t)src * D))[c];
                acc_bf8(acc, u);
            }
        }
    }

    // combine the 8 group partials (xor 8, 16, 32)
#pragma unroll
    for (int m = 8; m <= 32; m <<= 1) {
#pragma unroll
        for (int j = 0; j < 8; ++j) acc[j] += __shfl_xor(acc[j], m, 64);
    }

    if (g == 0) {                             // 8 lanes x 16 B = 128 B bf16 row
        uint4 p;
        p.x = pack2bf(acc[0], acc[1]);
        p.y = pack2bf(acc[2], acc[3]);
        p.z = pack2bf(acc[4], acc[5]);
        p.w = pack2bf(acc[6], acc[7]);
        ((uint4*)(x_out + (size_t)node * D))[c] = p;
    }
}

// ---------------------------------------------------------------------------
// MFMA conv: y = relu(x @ W^T + b) via mfma_f32_16x16x32_bf16, W in bf16
// hi/lo split (2 MFMAs per k-step -> fp32-accurate W). No X/W LDS staging:
// A-frags load straight from global x (lane: row=lane&15, k=(lane>>4)*8+j),
// B-frags from Whi/Wlo rows — W is 8 KB x2, L1/L2-hot across all blocks.
// C/D layout (m89-verified): col=lane&15, row=(lane>>4)*4+reg.
// 4 waves x 16 nodes = 64 nodes/block. Verified passing in R2.
// !SCORE: bf16 pack via LDS transpose -> coalesced uint4 stores.
// SCORE: fp32 y via LDS, wave0 per-node cosine vs pattern -> score_out.
template <bool SCORE>
__global__ __launch_bounds__(256) void conv_mfma_kernel(
        const unsigned short* __restrict__ x,
        const unsigned short* __restrict__ Whi,
        const unsigned short* __restrict__ Wlo,
        const float* __restrict__ b,
        const float* __restrict__ pattern_emb,
        const int* __restrict__ pattern_id,
        unsigned short* __restrict__ emb_out,
        float* __restrict__ score_out) {
    __shared__ union {
        unsigned short Os[CT][OS];   // 9216 B  (!SCORE epilogue)
        float Ys[CT][XS];            // 17408 B (SCORE epilogue)
    } u;
    __shared__ float ps[D];

    int t = threadIdx.x;
    int lane = t & 63;
    int wv = t >> 6;                          // wave 0..3
    int base = blockIdx.x * CT;
    int nodebase = base + wv * 16;
    int row16 = lane & 15;                    // A-row / B-col within tile
    int kq = lane >> 4;                       // k-quarter 0..3

    if (SCORE && t < D) ps[t] = pattern_emb[(size_t)pattern_id[0] * D + t];

    // A fragments (k-steps 0,1). Rows >= N_NODES (last block tail) read
    // in-workspace garbage; their outputs are predicated off below.
    const bf16x8* xp = (const bf16x8*)(x + (size_t)(nodebase + row16) * D + kq * 8);
    bf16x8 a0 = xp[0];                        // k = kq*8 .. +7
    bf16x8 a1 = xp[4];                        // k = 32 + kq*8 .. +7

    f32x4 acc[4] = {};
    float bj[4];
#pragma unroll
    for (int tc = 0; tc < 4; ++tc) {
        int o = tc * 16 + row16;              // output dim for this lane/tile
        bj[tc] = b[o];
        const bf16x8* wh = (const bf16x8*)(Whi + (size_t)o * D + kq * 8);
        const bf16x8* wl = (const bf16x8*)(Wlo + (size_t)o * D + kq * 8);
        acc[tc] = __builtin_amdgcn_mfma_f32_16x16x32_bf16(a0, wh[0], acc[tc], 0, 0, 0);
        acc[tc] = __builtin_amdgcn_mfma_f32_16x16x32_bf16(a1, wh[4], acc[tc], 0, 0, 0);
        acc[tc] = __builtin_amdgcn_mfma_f32_16x16x32_bf16(a0, wl[0], acc[tc], 0, 0, 0);
        acc[tc] = __builtin_amdgcn_mfma_f32_16x16x32_bf16(a1, wl[4], acc[tc], 0, 0, 0);
    }

    if (!SCORE) {
#pragma unroll
        for (int tc = 0; tc < 4; ++tc)
#pragma unroll
            for (int r = 0; r < 4; ++r)
                u.Os[wv * 16 + kq * 4 + r][tc * 16 + row16] =
                    f2bf(fmaxf(acc[tc][r] + bj[tc], 0.f));
        __syncthreads();
#pragma unroll
        for (int q = 0; q < 2; ++q) {
            int idx = t + q * 256;            // 0..511: 64 rows x 8 uint4 segs
            int r = idx >> 3, seg = idx & 7;
            int node = base + r;
            if (node < N_NODES)
                ((uint4*)(emb_out + (size_t)node * D))[seg] = *((const uint4*)&u.Os[r][8 * seg]);
        }
    } else {
#pragma unroll
        for (int tc = 0; tc < 4; ++tc)
#pragma unroll
            for (int r = 0; r < 4; ++r)
                u.Ys[wv * 16 + kq * 4 + r][tc * 16 + row16] = fmaxf(acc[tc][r] + bj[tc], 0.f);
        __syncthreads();
        if (t < CT) {                         // wave 0: one lane per node
            float dot = 0.f, n2 = 0.f, pn = 0.f;
#pragma unroll 8
            for (int k = 0; k < D; ++k) {
                float yk = u.Ys[t][k];
                float pk = ps[k];
                dot += yk * pk; n2 += yk * yk; pn += pk * pk;
            }
            int node = base + t;
            if (node < N_NODES)
                score_out[node] = dot / (fmaxf(sqrtf(n2), 1e-8f) * fmaxf(sqrtf(pn), 1e-8f));
        }
    }
}

// ---------------------------------------------------------------------------
// Fallback path (atomic scatter, full fp32) if ws too small for CSR arrays.
__global__ void init_embeds_kernel(const int* __restrict__ nodes,
                                   const float* __restrict__ features,
                                   const float* __restrict__ node_emb,
                                   const float* __restrict__ feat_W,
                                   const float* __restrict__ feat_b,
                                   float* __restrict__ embeds) {
    int tid = blockIdx.x * blockDim.x + threadIdx.x;
    if (tid >= N_NODES * D) return;
    int node = tid >> 6;
    int d = tid & 63;
    float acc = feat_b[d];
    const float* f = features + (size_t)node * 10;
    const float* w = feat_W + (size_t)d * 10;
#pragma unroll
    for (int j = 0; j < 10; ++j) acc += f[j] * w[j];
    embeds[tid] = node_emb[(size_t)nodes[node] * D + d] + acc;
}

__global__ void scatter_add_kernel(const int* __restrict__ edges,
                                   const float* __restrict__ embeds,
                                   float* __restrict__ agg) {
    int tid = blockIdx.x * blockDim.x + threadIdx.x;
    int edge = tid >> 6;
    int lane = tid & 63;
    if (edge >= N_EDGES) return;
    int src = edges[2 * edge + 0];
    int dst = edges[2 * edge + 1];
    atomicAdd(&agg[(size_t)dst * D + lane], embeds[(size_t)src * D + lane]);
}

__global__ void conv_inplace_kernel(const float* __restrict__ agg,
                                    const float* __restrict__ W,
                                    const float* __restrict__ b,
                                    float* __restrict__ embeds) {
    __shared__ float Ws[D * 65];
    __shared__ float xs[4][D];
    for (int i = threadIdx.x; i < D * D; i += blockDim.x) {
        int d = i >> 6, k = i & 63;
        Ws[d * 65 + k] = W[i];
    }
    __syncthreads();
    int lane_d = threadIdx.x & 63;
    int local_n = threadIdx.x >> 6;
    float bias = b[lane_d];
    const int n_chunks = (N_NODES + 3) / 4;
    for (int chunk = blockIdx.x; chunk < n_chunks; chunk += gridDim.x) {
        int node = chunk * 4 + local_n;
        if (node < N_NODES) {
            size_t base = (size_t)node * D + lane_d;
            xs[local_n][lane_d] = embeds[base] + agg[base];
        }
        __syncthreads();
        if (node < N_NODES) {
            float acc = bias;
#pragma unroll
            for (int k = 0; k < D; ++k) acc += xs[local_n][k] * Ws[lane_d * 65 + k];
            embeds[(size_t)node * D + lane_d] = fmaxf(acc, 0.0f);
        }
        __syncthreads();
    }
}

__global__ void final_score_kernel(const float* __restrict__ embeds,
                                   const float* __restrict__ pattern_emb,
                                   const int* __restrict__ pattern_id,
                                   float* __restrict__ out) {
    int lane = threadIdx.x & 63;
    int wave = threadIdx.x >> 6;
    int node = blockIdx.x * 4 + wave;
    int pid = pattern_id[0];
    float p = pattern_emb[(size_t)pid * D + lane];
    float pn = p * p;
#pragma unroll
    for (int m = 32; m > 0; m >>= 1) pn += __shfl_xor(pn, m, 64);
    if (node < N_NODES) {
        float e = embeds[(size_t)node * D + lane];
        float dot = e * p;
        float n2 = e * e;
#pragma unroll
        for (int m = 32; m > 0; m >>= 1) {
            dot += __shfl_xor(dot, m, 64);
            n2  += __shfl_xor(n2, m, 64);
        }
        if (lane == 0) {
            float denom = fmaxf(sqrtf(n2), 1e-8f) * fmaxf(sqrtf(pn), 1e-8f);
            out[node] = dot / denom;
        }
    }
}

// ---------------------------------------------------------------------------
extern "C" void kernel_launch(void* const* d_in, const int* in_sizes, int n_in,
                              void* d_out, int out_size, void* d_ws, size_t ws_size,
                              hipStream_t stream) {
    const int*   nodes       = (const int*)d_in[0];
    const int*   edges       = (const int*)d_in[1];
    const float* features    = (const float*)d_in[2];
    const float* node_emb    = (const float*)d_in[3];
    const float* feat_W      = (const float*)d_in[4];
    const float* feat_b      = (const float*)d_in[5];
    const float* conv1_W     = (const float*)d_in[6];
    const float* conv1_b     = (const float*)d_in[7];
    const float* pattern_emb = (const float*)d_in[8];
    const int*   pattern_id  = (const int*)d_in[9];
    float* out = (float*)d_out;

    const size_t emb_f32_bytes = (size_t)N_NODES * D * sizeof(float);   // 25.6 MB
    const size_t emb_bf_bytes  = (size_t)N_NODES * D * 2;               // 12.8 MB
    auto align256 = [](size_t x) { return (x + 255) & ~(size_t)255; };

    size_t o_embA = 0;
    size_t o_embB = o_embA + align256(emb_bf_bytes);
    size_t o_xbuf = o_embB + align256(emb_bf_bytes);
    size_t o_col  = o_xbuf + align256(emb_bf_bytes);
    size_t o_rank = o_col  + align256((size_t)N_EDGES * 4);
    size_t o_row  = o_rank + align256((size_t)N_EDGES * 4);
    size_t o_deg  = o_row  + align256((size_t)(N_NODES + 1) * 4);
    size_t o_bsum = o_deg  + align256((size_t)N_NODES * 4);
    size_t o_whi  = o_bsum + align256((size_t)NB1 * 4);
    size_t o_wlo  = o_whi  + align256((size_t)D * D * 2);
    size_t need   = o_wlo  + align256((size_t)D * D * 2);

    char* ws = (char*)d_ws;

    if (ws_size >= need) {
        unsigned short* embA = (unsigned short*)(ws + o_embA);
        unsigned short* embB = (unsigned short*)(ws + o_embB);
        unsigned short* xbuf = (unsigned short*)(ws + o_xbuf);
        int*   col  = (int*)(ws + o_col);
        int*   rank = (int*)(ws + o_rank);
        int*   rowp = (int*)(ws + o_row);
        int*   deg  = (int*)(ws + o_deg);
        int*   bsum = (int*)(ws + o_bsum);
        unsigned short* Whi = (unsigned short*)(ws + o_whi);
        unsigned short* Wlo = (unsigned short*)(ws + o_wlo);

        hipMemsetAsync(deg, 0, (size_t)N_NODES * 4, stream);
        hist_rank_kernel<<<FILL_BLOCKS, 256, 0, stream>>>((const int2*)edges, deg, rank);
        scan1_kernel<<<NB1, SCAN_B, 0, stream>>>(deg, rowp, bsum);
        scan23_kernel<<<NB1, SCAN_B, 0, stream>>>(rowp, bsum);
        fill_init_kernel<<<FILL_BLOCKS + INIT_BLOCKS + 1, 256, 0, stream>>>(
            (const int2*)edges, rank, rowp, col,
            nodes, features, node_emb, feat_W, feat_b, embA,
            conv1_W, Whi, Wlo);

        const int conv_grid = (N_NODES + CT - 1) / CT;   // 1563

        // iter 1: gather(bf16->bf16) + MFMA conv -> embB (bf16)
        gather_x_kernel<<<N_NODES / 4, 256, 0, stream>>>(embA, rowp, col, xbuf);
        conv_mfma_kernel<false><<<conv_grid, 256, 0, stream>>>(
            xbuf, Whi, Wlo, conv1_b, pattern_emb, pattern_id, embB, nullptr);
        // iter 2: gather + MFMA conv fused with cosine score -> out
        gather_x_kernel<<<N_NODES / 4, 256, 0, stream>>>(embB, rowp, col, xbuf);
        conv_mfma_kernel<true><<<conv_grid, 256, 0, stream>>>(
            xbuf, Whi, Wlo, conv1_b, pattern_emb, pattern_id, nullptr, out);
    } else {
        float* embeds = (float*)ws;
        float* agg = (float*)(ws + align256(emb_f32_bytes));
        init_embeds_kernel<<<(N_NODES * D + 255) / 256, 256, 0, stream>>>(
            nodes, features, node_emb, feat_W, feat_b, embeds);
        for (int it = 0; it < 2; ++it) {
            hipMemsetAsync(agg, 0, emb_f32_bytes, stream);
            long long total = (long long)N_EDGES * 64;
            scatter_add_kernel<<<(int)((total + 255) / 256), 256, 0, stream>>>(edges, embeds, agg);
            conv_inplace_kernel<<<2048, 256, 0, stream>>>(agg, conv1_W, conv1_b, embeds);
        }
        final_score_kernel<<<(N_NODES + 3) / 4, 256, 0, stream>>>(
            embeds, pattern_emb, pattern_id, out);
    }
}